// Round 1
// 1014.613 us; speedup vs baseline: 1.0561x; 1.0561x over previous
//
#include <hip/hip_runtime.h>

// LocalConvolution: out[b,o,i,j] = sum_{c,u,v} x[b,c,i+u,j+v] * w[i,j,o,c,u,v]
// x: [64,64,32,32] f32 (16 MB, L3-resident) ; w: [28,28,128,64,5,5] f32 (642 MB,
// streamed exactly once) ; out: [64,128,28,28] f32 (26 MB).
// Per-position GEMM M=64(b), N=128(o), K=1600, bf16 MFMA 16x16x32.
//
// Round-4 (fused): eliminate pack_x + P workspace (was +459 MB HBM + a 5 GB
// L2-amplified gather dispatch). The A-tile [64b][160k] is now built INSIDE the
// GEMM kernel, double-buffered, directly from x:
//   - k-chunks of 160 are multiples of 5 -> every 5-elem patch row (b,c,u) lies
//     wholly in one chunk. Thread (b, quarter q) builds rows rr=q*8..q*8+7 of
//     its chunk: per row two ALIGNED float4 loads cover x[b][c][i+u][j..j+4]
//     (32 B from L2/L3 instead of 5 scalar gathers), f2bf, then 5 aligned
//     ds_write_b128 (80 B contiguous) -- identical LDS image to the old pack.
//   - j&3 misalignment is block-uniform -> templated run_block<DJ> (keeps all
//     register arrays statically indexed; uniform branch is free).
//   - Weight path / MFMA / epilogue unchanged from the verified round-3 kernel
//     (wr[10] dwordx4 hoist per chunk, 20 MFMA, plain split-N stores).
// Traffic floor: 642(w) + ~16(x, L3) + 26(out) MB ~= 109 us @ 6.3 TB/s.

typedef __attribute__((ext_vector_type(8))) short bf16x8;
typedef __attribute__((ext_vector_type(4))) float f32x4;
typedef unsigned int u32;
typedef unsigned short u16;

__device__ __forceinline__ u16 f2bf(float f) {
    u32 u = __float_as_uint(f);
    u = (u + 0x7fffu + ((u >> 16) & 1u)) >> 16;   // RNE
    return (u16)u;
}

template<int DJ>
__device__ __forceinline__ void run_block(const float* __restrict__ xb,
                                          const float* __restrict__ wrow,
                                          float* __restrict__ outp,
                                          u16* As0, u16* As1,
                                          int tb, int q, int l15, int quad) {
    constexpr int KC = 160;                       // 5 MFMA k-steps per chunk

    // ---- build chunk cb of the A-tile into dstbuf ----
    // rows rr = q*8+rw ; R = cb*32+rr ; c = R/5 ; u = R%5 ; k = R*5+v.
    // Writes bytes [q*80, q*80+80) of LDS row tb (16B-aligned b128 stores).
    auto build = [&](int cb, u16* dstbuf) {
        u16 bu[40];
#pragma unroll
        for (int half = 0; half < 2; ++half) {    // 2x4 rows: caps VGPR pressure
            float fr[4][8];
#pragma unroll
            for (int rw = 0; rw < 4; ++rw) {
                const int R = cb * 32 + q * 8 + half * 4 + rw;
                const int c = R / 5, u = R - 5 * c;
                const float* p = xb + c * 1024 + u * 32;
                *(f32x4*)&fr[rw][0] = *(const f32x4*)(p);
                *(f32x4*)&fr[rw][4] = *(const f32x4*)(p + 4);
            }
#pragma unroll
            for (int rw = 0; rw < 4; ++rw)
#pragma unroll
                for (int v = 0; v < 5; ++v)
                    bu[(half * 4 + rw) * 5 + v] = f2bf(fr[rw][DJ + v]);
        }
        u16* dst = dstbuf + tb * KC + q * 40;
#pragma unroll
        for (int r = 0; r < 5; ++r)
            *(uint4*)(dst + r * 8) = *(const uint4*)&bu[r * 8];
    };

    f32x4 acc[4];
#pragma unroll
    for (int mt = 0; mt < 4; ++mt) acc[mt] = (f32x4)0.f;

    build(0, As0);
    __syncthreads();

    for (int cb = 0; cb < 10; ++cb) {
        // ---- hoist ALL weight loads for this chunk (10 dwordx4 in flight) ----
        const float* wc = wrow + cb * 160;
        f32x4 wr[10];
#pragma unroll
        for (int ks = 0; ks < 5; ++ks) {
            wr[2 * ks]     = *(const f32x4*)(wc + ks * 32);
            wr[2 * ks + 1] = *(const f32x4*)(wc + ks * 32 + 4);
        }
        // ---- build next chunk into the other buffer (hides under weights) ----
        if (cb < 9) build(cb + 1, (cb & 1) ? As0 : As1);

        const u16* A = (cb & 1) ? As1 : As0;
#pragma unroll
        for (int ks = 0; ks < 5; ++ks) {
            f32x4 w0 = wr[2 * ks], w1 = wr[2 * ks + 1];
            bf16x8 bv;
            bv[0] = (short)f2bf(w0[0]); bv[1] = (short)f2bf(w0[1]);
            bv[2] = (short)f2bf(w0[2]); bv[3] = (short)f2bf(w0[3]);
            bv[4] = (short)f2bf(w1[0]); bv[5] = (short)f2bf(w1[1]);
            bv[6] = (short)f2bf(w1[2]); bv[7] = (short)f2bf(w1[3]);
#pragma unroll
            for (int mt = 0; mt < 4; ++mt) {
                bf16x8 av = *(const bf16x8*)&A[(mt * 16 + l15) * KC + ks * 32 + quad * 8];
                acc[mt] = __builtin_amdgcn_mfma_f32_16x16x32_bf16(av, bv, acc[mt], 0, 0, 0);
            }
        }
        if (cb < 9) __syncthreads();
    }

    // ---- epilogue: D[m=quad*4+r][n=l15] -> out[b][o][g], plain stores ----
#pragma unroll
    for (int mt = 0; mt < 4; ++mt)
#pragma unroll
        for (int r = 0; r < 4; ++r) {
            const int b = mt * 16 + quad * 4 + r;
            outp[(size_t)b * 100352] = acc[mt][r];   // 100352 = 128*784
        }
}

__global__ __launch_bounds__(256, 3) void lconv_fused(const float* __restrict__ x,
                                                      const float* __restrict__ wgt,
                                                      float* __restrict__ out) {
    __shared__ u16 As[2][64 * 160];                // 2 x 20480 B

    const int bx = blockIdx.x;
    // s-pair (o-halves of same g) and g-neighbors land on the same XCD:
    const int s  = (bx >> 3) & 1;                  // o-half
    const int bq = (bx & 7) | ((bx >> 4) << 3);
    const int g  = (bq & 7) * 98 + (bq >> 3);      // XCD swizzle over positions
    const int i = g / 28, j = g - i * 28;
    const int j0 = j & ~3;                         // aligned col base; dj = j&3

    const int t = threadIdx.x, lane = t & 63, wv = t >> 6;
    const int l15 = lane & 15, quad = lane >> 4;
    const int tb = t >> 2, q = t & 3;              // build role: (batch, quarter)

    const float* xb = x + tb * 65536 + i * 32 + j0;
    const float* wrow = wgt + (size_t)g * 204800
                      + (size_t)(s * 64 + wv * 16 + l15) * 1600 + quad * 8;
    const int o = s * 64 + wv * 16 + l15;
    float* outp = out + (size_t)o * 784 + g;

    switch (j & 3) {                               // block-uniform branch
        case 0:  run_block<0>(xb, wrow, outp, &As[0][0], &As[1][0], tb, q, l15, quad); break;
        case 1:  run_block<1>(xb, wrow, outp, &As[0][0], &As[1][0], tb, q, l15, quad); break;
        case 2:  run_block<2>(xb, wrow, outp, &As[0][0], &As[1][0], tb, q, l15, quad); break;
        default: run_block<3>(xb, wrow, outp, &As[0][0], &As[1][0], tb, q, l15, quad); break;
    }
}

extern "C" void kernel_launch(void* const* d_in, const int* in_sizes, int n_in,
                              void* d_out, int out_size, void* d_ws, size_t ws_size,
                              hipStream_t stream) {
    const float* x   = (const float*)d_in[0];
    const float* wgt = (const float*)d_in[1];
    float* out       = (float*)d_out;
    (void)d_ws; (void)ws_size;                     // workspace no longer used
    lconv_fused<<<1568, 256, 0, stream>>>(x, wgt, out);
}